// Round 1
// baseline (44.964 us; speedup 1.0000x reference)
//
#include <hip/hip_runtime.h>

#define LSTREAM 512
#define C 8
#define OUTD 584  // 8 + 64 + 512

__global__ __launch_bounds__(64) void sig_kernel(const float* __restrict__ path,
                                                 float* __restrict__ out) {
    __shared__ float lds[LSTREAM * C];  // 16 KB: one batch's full path
    const int b = blockIdx.x;
    const int lane = threadIdx.x;

    const float* p = path + (size_t)b * (LSTREAM * C);
    // cooperative load: 4096 floats = 1024 float4, 64 lanes -> 16 iters, coalesced
    #pragma unroll
    for (int it = 0; it < (LSTREAM * C / 4) / 64; ++it) {
        int idx = it * 64 + lane;
        reinterpret_cast<float4*>(lds)[idx] = reinterpret_cast<const float4*>(p)[idx];
    }
    __syncthreads();

    const int i = lane >> 3;   // first tensor index
    const int j = lane & 7;    // second tensor index

    float s1i = 0.f;           // sig1[i] (replicated across the 8 lanes sharing i)
    float s2  = 0.f;           // sig2[i*8+j]
    float s3[C];               // sig3[i*64+j*8+k] = sig3[lane*8+k]
    #pragma unroll
    for (int k = 0; k < C; ++k) s3[k] = 0.f;

    float prev[C];
    #pragma unroll
    for (int k = 0; k < C; ++k) prev[k] = lds[k];
    float pi_prev = lds[i];
    float pj_prev = lds[j];

    #pragma unroll 4
    for (int t = 1; t < LSTREAM; ++t) {
        // broadcast read of row t (all lanes same address -> no conflict)
        const float4 a = reinterpret_cast<const float4*>(lds)[t * 2];
        const float4 c = reinterpret_cast<const float4*>(lds)[t * 2 + 1];
        float nxt[C] = {a.x, a.y, a.z, a.w, c.x, c.y, c.z, c.w};
        float dx[C];
        #pragma unroll
        for (int k = 0; k < C; ++k) { dx[k] = nxt[k] - prev[k]; prev[k] = nxt[k]; }
        // per-lane scalar reads (8 distinct addrs, 8 banks, 8-lane broadcast: conflict-free)
        const float pi = lds[t * C + i];
        const float pj = lds[t * C + j];
        const float dxi = pi - pi_prev; pi_prev = pi;
        const float dxj = pj - pj_prev; pj_prev = pj;

        const float u  = dxi * dxj;   // dx_i * dx_j
        const float t1 = s1i * dxj;   // sig1[i] * dx_j
        // level-3 update: sig3[k] += (dx_i dx_j/6 + sig1_i dx_j/2 + sig2) * dx_k
        const float coeff = u * (1.f / 6.f) + t1 * 0.5f + s2;
        #pragma unroll
        for (int k = 0; k < C; ++k) s3[k] = fmaf(coeff, dx[k], s3[k]);
        // level-2 update (uses OLD sig1): sig2 += dx_i dx_j/2 + sig1_i dx_j
        s2 += u * 0.5f + t1;
        // level-1 update
        s1i += dxi;
    }

    // output layout per batch: [sig1 (8) | sig2 (64) | sig3 (512)]
    float* ob = out + (size_t)b * OUTD;
    // sig1[c] lives on lanes [8c, 8c+8); lane<8 gathers channel `lane` from lane 8*lane
    float s1out = __shfl(s1i, (lane << 3) & 63, 64);
    if (lane < C) ob[lane] = s1out;
    ob[C + lane] = s2;
    #pragma unroll
    for (int k = 0; k < C; ++k) ob[C + 64 + lane * C + k] = s3[k];
}

extern "C" void kernel_launch(void* const* d_in, const int* in_sizes, int n_in,
                              void* d_out, int out_size, void* d_ws, size_t ws_size,
                              hipStream_t stream) {
    const float* path = (const float*)d_in[0];
    float* out = (float*)d_out;
    const int B = in_sizes[0] / (LSTREAM * C);
    sig_kernel<<<B, 64, 0, stream>>>(path, out);
}

// Round 2
// 18.343 us; speedup vs baseline: 2.4513x; 2.4513x over previous
//
#include <hip/hip_runtime.h>

#define LSTREAM 512
#define C 8
#define OUTD 584   // 8 + 64 + 512
#define NW 8       // waves per block (segments per batch)
#define SEG 64     // increments per segment (last wave does 63)
#define PSTRIDE 600 // partial-signature stride in floats (584 padded, keeps 16B align)

// Chen combine: state (a, in regs) <- a (x) b (in LDS at bp).
// a is earlier in time. Lane = i*8+j owns a2[i][j] (s2) and a3[i][j][0..7] (s3),
// s1i = a1[i] replicated across the 8 lanes sharing i.
__device__ __forceinline__ void chen_combine(const float* bp, int i, int j, int lane,
                                             float& s1i, float& s2, float (&s3)[C]) {
    const float  b1i  = bp[i];
    const float  b1j  = bp[j];
    const float4 b1lo = *reinterpret_cast<const float4*>(bp);
    const float4 b1hi = *reinterpret_cast<const float4*>(bp + 4);
    const float4 b2lo = *reinterpret_cast<const float4*>(bp + C + j * C);
    const float4 b2hi = *reinterpret_cast<const float4*>(bp + C + j * C + 4);
    const float  b2ij = bp[C + lane];
    const float4 b3lo = *reinterpret_cast<const float4*>(bp + C + 64 + lane * C);
    const float4 b3hi = *reinterpret_cast<const float4*>(bp + C + 64 + lane * C + 4);
    const float b1k[C]  = {b1lo.x, b1lo.y, b1lo.z, b1lo.w, b1hi.x, b1hi.y, b1hi.z, b1hi.w};
    const float b2jk[C] = {b2lo.x, b2lo.y, b2lo.z, b2lo.w, b2hi.x, b2hi.y, b2hi.z, b2hi.w};
    const float b3k[C]  = {b3lo.x, b3lo.y, b3lo.z, b3lo.w, b3hi.x, b3hi.y, b3hi.z, b3hi.w};
    // use OLD s1i, s2 for level-3; OLD s1i for level-2; update order matters
    #pragma unroll
    for (int k = 0; k < C; ++k)
        s3[k] = s3[k] + b3k[k] + s1i * b2jk[k] + s2 * b1k[k];
    s2 = s2 + b2ij + s1i * b1j;
    s1i += b1i;
}

__device__ __forceinline__ void store_partial(float* pp, int i, int j, int lane,
                                              float s1i, float s2, const float (&s3)[C]) {
    if (j == 0) pp[i] = s1i;          // lanes i*8 hold a1[i]
    pp[C + lane] = s2;
    #pragma unroll
    for (int k = 0; k < C; ++k) pp[C + 64 + lane * C + k] = s3[k];
}

__global__ __launch_bounds__(512) void sig_kernel(const float* __restrict__ path,
                                                  float* __restrict__ out) {
    __shared__ float lds[LSTREAM * C];      // 16 KB: full path for this batch
    __shared__ float part[NW * PSTRIDE];    // 18.75 KB: per-wave partial signatures
    const int b    = blockIdx.x;
    const int tid  = threadIdx.x;
    const int w    = tid >> 6;
    const int lane = tid & 63;

    const float* p = path + (size_t)b * (LSTREAM * C);
    // cooperative load: 1024 float4 / 512 threads = 2 each, coalesced
    #pragma unroll
    for (int it = 0; it < (LSTREAM * C / 4) / 512; ++it) {
        int idx = it * 512 + tid;
        reinterpret_cast<float4*>(lds)[idx] = reinterpret_cast<const float4*>(p)[idx];
    }
    __syncthreads();

    const int i = lane >> 3;
    const int j = lane & 7;

    float s1i = 0.f, s2 = 0.f;
    float s3[C];
    #pragma unroll
    for (int k = 0; k < C; ++k) s3[k] = 0.f;

    // wave w handles increments t in (r0, r1]: rows r0..r1
    const int r0 = w * SEG;
    const int r1 = (w == NW - 1) ? (LSTREAM - 1) : (r0 + SEG);

    float prev[C];
    {
        const float4 a0 = reinterpret_cast<const float4*>(lds)[r0 * 2];
        const float4 c0 = reinterpret_cast<const float4*>(lds)[r0 * 2 + 1];
        prev[0]=a0.x; prev[1]=a0.y; prev[2]=a0.z; prev[3]=a0.w;
        prev[4]=c0.x; prev[5]=c0.y; prev[6]=c0.z; prev[7]=c0.w;
    }
    float pi_prev = lds[r0 * C + i];
    float pj_prev = lds[r0 * C + j];

    #pragma unroll 4
    for (int t = r0 + 1; t <= r1; ++t) {
        const float4 a = reinterpret_cast<const float4*>(lds)[t * 2];
        const float4 c = reinterpret_cast<const float4*>(lds)[t * 2 + 1];
        float nxt[C] = {a.x, a.y, a.z, a.w, c.x, c.y, c.z, c.w};
        float dx[C];
        #pragma unroll
        for (int k = 0; k < C; ++k) { dx[k] = nxt[k] - prev[k]; prev[k] = nxt[k]; }
        const float pi = lds[t * C + i];
        const float pj = lds[t * C + j];
        const float dxi = pi - pi_prev; pi_prev = pi;
        const float dxj = pj - pj_prev; pj_prev = pj;

        const float u  = dxi * dxj;
        const float t1 = s1i * dxj;
        const float coeff = u * (1.f / 6.f) + t1 * 0.5f + s2;
        #pragma unroll
        for (int k = 0; k < C; ++k) s3[k] = fmaf(coeff, dx[k], s3[k]);
        s2 += u * 0.5f + t1;
        s1i += dxi;
    }

    // publish all partials
    store_partial(part + w * PSTRIDE, i, j, lane, s1i, s2, s3);
    __syncthreads();

    // tree combine: 8 -> 4 -> 2 -> 1 (active waves keep result in regs)
    // level 1: waves 0,2,4,6 combine with partner w+1
    if ((w & 1) == 0) chen_combine(part + (w + 1) * PSTRIDE, i, j, lane, s1i, s2, s3);
    if (w == 2 || w == 6) store_partial(part + w * PSTRIDE, i, j, lane, s1i, s2, s3);
    __syncthreads();

    // level 2: waves 0,4 combine with partner w+2
    if ((w & 3) == 0) chen_combine(part + (w + 2) * PSTRIDE, i, j, lane, s1i, s2, s3);
    if (w == 4) store_partial(part + w * PSTRIDE, i, j, lane, s1i, s2, s3);
    __syncthreads();

    // level 3: wave 0 combines with wave 4's result, then writes out
    if (w == 0) {
        chen_combine(part + 4 * PSTRIDE, i, j, lane, s1i, s2, s3);
        float* ob = out + (size_t)b * OUTD;
        const float s1out = __shfl(s1i, (lane << 3) & 63, 64);
        if (lane < C) ob[lane] = s1out;
        ob[C + lane] = s2;
        #pragma unroll
        for (int k = 0; k < C; ++k) ob[C + 64 + lane * C + k] = s3[k];
    }
}

extern "C" void kernel_launch(void* const* d_in, const int* in_sizes, int n_in,
                              void* d_out, int out_size, void* d_ws, size_t ws_size,
                              hipStream_t stream) {
    const float* path = (const float*)d_in[0];
    float* out = (float*)d_out;
    const int B = in_sizes[0] / (LSTREAM * C);
    sig_kernel<<<B, 512, 0, stream>>>(path, out);
}

// Round 3
// 15.430 us; speedup vs baseline: 2.9140x; 1.1888x over previous
//
#include <hip/hip_runtime.h>

#define LSTREAM 512
#define C 8
#define OUTD 584    // 8 + 64 + 512
#define NW 16       // waves per block (segments per batch)
#define SEG 32      // increments per segment (last wave does 31)
#define INCF 4096   // inc buffer floats (511*8 rounded up)
#define PSTRIDE 600 // partial-signature stride in floats

// Chen combine: state (a, in regs) <- a (x) b (in LDS at bp). a is earlier.
// Lane = i*8+j owns a2[i][j] (s2), a3[i][j][0..7] (s3); s1i = a1[i].
__device__ __forceinline__ void chen_combine(const float* bp, int i, int j, int lane,
                                             float& s1i, float& s2, float (&s3)[C]) {
    const float  b1i  = bp[i];
    const float  b1j  = bp[j];
    const float4 b1lo = *reinterpret_cast<const float4*>(bp);
    const float4 b1hi = *reinterpret_cast<const float4*>(bp + 4);
    const float4 b2lo = *reinterpret_cast<const float4*>(bp + C + j * C);
    const float4 b2hi = *reinterpret_cast<const float4*>(bp + C + j * C + 4);
    const float  b2ij = bp[C + lane];
    const float4 b3lo = *reinterpret_cast<const float4*>(bp + C + 64 + lane * C);
    const float4 b3hi = *reinterpret_cast<const float4*>(bp + C + 64 + lane * C + 4);
    const float b1k[C]  = {b1lo.x, b1lo.y, b1lo.z, b1lo.w, b1hi.x, b1hi.y, b1hi.z, b1hi.w};
    const float b2jk[C] = {b2lo.x, b2lo.y, b2lo.z, b2lo.w, b2hi.x, b2hi.y, b2hi.z, b2hi.w};
    const float b3k[C]  = {b3lo.x, b3lo.y, b3lo.z, b3lo.w, b3hi.x, b3hi.y, b3hi.z, b3hi.w};
    #pragma unroll
    for (int k = 0; k < C; ++k)
        s3[k] = s3[k] + b3k[k] + s1i * b2jk[k] + s2 * b1k[k];
    s2 = s2 + b2ij + s1i * b1j;
    s1i += b1i;
}

__device__ __forceinline__ void store_partial(float* pp, int i, int j, int lane,
                                              float s1i, float s2, const float (&s3)[C]) {
    if (j == 0) pp[i] = s1i;
    pp[C + lane] = s2;
    #pragma unroll
    for (int k = 0; k < C; ++k) pp[C + 64 + lane * C + k] = s3[k];
}

__global__ __launch_bounds__(1024, 8) void sig_kernel(const float* __restrict__ path,
                                                      float* __restrict__ out) {
    __shared__ float inc[INCF];            // 16 KB: increment rows 0..510
    __shared__ float part[NW * PSTRIDE];   // 37.5 KB: per-wave partial signatures
    const int b    = blockIdx.x;
    const int tid  = threadIdx.x;
    const int w    = tid >> 6;
    const int lane = tid & 63;

    // ---- pre-pass: compute increments straight from global (coalesced) ----
    // thread handles half a row: row = tid>>1, half = tid&1
    {
        const int row = tid >> 1;
        if (row < LSTREAM - 1) {
            const float4* p4 = reinterpret_cast<const float4*>(path + (size_t)b * (LSTREAM * C));
            const float4 a = p4[tid];       // (row, half)
            const float4 c = p4[tid + 2];   // (row+1, half)
            float4 d;
            d.x = c.x - a.x; d.y = c.y - a.y; d.z = c.z - a.z; d.w = c.w - a.w;
            reinterpret_cast<float4*>(inc)[tid] = d;
        }
    }
    __syncthreads();

    const int i = lane >> 3;
    const int j = lane & 7;

    float s1i = 0.f, s2 = 0.f;
    float s3[C];
    #pragma unroll
    for (int k = 0; k < C; ++k) s3[k] = 0.f;

    // wave w consumes inc rows [w*SEG, min(w*SEG+SEG, 511))
    const int r0 = w * SEG;
    const int nst = min(SEG, (LSTREAM - 1) - r0);

    const float* ib = inc + r0 * C;
    #pragma unroll 4
    for (int t = 0; t < nst; ++t, ib += C) {
        const float4 a = *reinterpret_cast<const float4*>(ib);
        const float4 c = *reinterpret_cast<const float4*>(ib + 4);
        const float dx[C] = {a.x, a.y, a.z, a.w, c.x, c.y, c.z, c.w};
        const float dxi = ib[i];
        const float dxj = ib[j];

        const float u  = dxi * dxj;
        const float t1 = s1i * dxj;
        const float coeff = fmaf(u, (1.f / 6.f), fmaf(t1, 0.5f, s2));
        #pragma unroll
        for (int k = 0; k < C; ++k) s3[k] = fmaf(coeff, dx[k], s3[k]);
        s2 = fmaf(u, 0.5f, s2) + t1;
        s1i += dxi;
    }

    // ---- publish partials, tree-combine 16 -> 1 ----
    store_partial(part + w * PSTRIDE, i, j, lane, s1i, s2, s3);
    __syncthreads();

    if ((w & 1) == 0) chen_combine(part + (w + 1) * PSTRIDE, i, j, lane, s1i, s2, s3);
    if (w == 2 || w == 6 || w == 10 || w == 14)
        store_partial(part + w * PSTRIDE, i, j, lane, s1i, s2, s3);
    __syncthreads();

    if ((w & 3) == 0) chen_combine(part + (w + 2) * PSTRIDE, i, j, lane, s1i, s2, s3);
    if (w == 4 || w == 12)
        store_partial(part + w * PSTRIDE, i, j, lane, s1i, s2, s3);
    __syncthreads();

    if ((w & 7) == 0) chen_combine(part + (w + 4) * PSTRIDE, i, j, lane, s1i, s2, s3);
    if (w == 8)
        store_partial(part + w * PSTRIDE, i, j, lane, s1i, s2, s3);
    __syncthreads();

    if (w == 0) {
        chen_combine(part + 8 * PSTRIDE, i, j, lane, s1i, s2, s3);
        float* ob = out + (size_t)b * OUTD;
        const float s1out = __shfl(s1i, (lane << 3) & 63, 64);
        if (lane < C) ob[lane] = s1out;
        ob[C + lane] = s2;
        #pragma unroll
        for (int k = 0; k < C; ++k) ob[C + 64 + lane * C + k] = s3[k];
    }
}

extern "C" void kernel_launch(void* const* d_in, const int* in_sizes, int n_in,
                              void* d_out, int out_size, void* d_ws, size_t ws_size,
                              hipStream_t stream) {
    const float* path = (const float*)d_in[0];
    float* out = (float*)d_out;
    const int B = in_sizes[0] / (LSTREAM * C);
    sig_kernel<<<B, 1024, 0, stream>>>(path, out);
}